// Round 5
// baseline (577.117 us; speedup 1.0000x reference)
//
#include <hip/hip_runtime.h>
#include <math.h>

#define Bn 64
#define In 2048
#define On 2048
#define Sn 10
#define Cn 512

typedef float f32x4 __attribute__((ext_vector_type(4)));
typedef float f32x2 __attribute__((ext_vector_type(2)));

__device__ __forceinline__ float sigmoidf_(float x) { return 1.0f / (1.0f + expf(-x)); }

// blocks 0..63: ctx mean -> ws_ctx[64]
// blocks 64..95: x [64][2048] -> xT [2048][64] (fp32 transpose via LDS)
// blocks 96..607: effw[o][i] = prune(wgt, cst, thr)  (coalesced stream)
__global__ __launch_bounds__(256)
void prep_kernel(const float* __restrict__ x,
                 const float* __restrict__ ctx,
                 const float* __restrict__ wgt,
                 const float* __restrict__ cst,
                 const float* __restrict__ prn,
                 float* __restrict__ ws_ctx,
                 float* __restrict__ xT,
                 float* __restrict__ effw) {
    const int b = blockIdx.x;
    const int t = threadIdx.x;
    if (b < Bn) {
        __shared__ float red[256];
        float s = ctx[b * Cn + t] + ctx[b * Cn + t + 256];
        red[t] = s;
        __syncthreads();
        for (int off = 128; off > 0; off >>= 1) {
            if (t < off) red[t] += red[t + off];
            __syncthreads();
        }
        if (t == 0) ws_ctx[b] = red[0] * (1.0f / (float)Cn);
    } else if (b < Bn + 32) {
        // transpose a [64 b] x [64 i] tile
        __shared__ float T[64][65];
        const int i0 = (b - Bn) * 64;
        const int row = t >> 4;            // 0..15
        const int col4 = (t & 15) * 4;     // 0..60
#pragma unroll
        for (int r = 0; r < 4; ++r) {
            const int rr = row + r * 16;   // b index 0..63
            f32x4 v = *(const f32x4*)(x + (size_t)rr * In + i0 + col4);
            T[col4 + 0][rr] = v[0];
            T[col4 + 1][rr] = v[1];
            T[col4 + 2][rr] = v[2];
            T[col4 + 3][rr] = v[3];
        }
        __syncthreads();
        const int il = t >> 2;             // i-local 0..63
        const int c = (t & 3) * 16;        // 0,16,32,48
        float* dst = xT + (size_t)(i0 + il) * Bn + c;
#pragma unroll
        for (int k = 0; k < 16; k += 4)
            *(f32x4*)(dst + k) = *(const f32x4*)(&T[il][c + k]);
    } else {
        // effw: 512 blocks x 8192 floats, fully coalesced float4 stream
        const float thr = prn[0];
        const size_t base = (size_t)(b - Bn - 32) * 8192;
#pragma unroll
        for (int k = 0; k < 8; ++k) {
            const size_t idx = base + ((size_t)k * 256 + t) * 4;
            f32x4 w = *(const f32x4*)(wgt + idx);
            f32x4 c4 = *(const f32x4*)(cst + idx);
            f32x4 e;
#pragma unroll
            for (int j = 0; j < 4; ++j)
                e[j] = (__builtin_fabsf(w[j]) * c4[j] > thr) ? w[j] : 0.0f;
            *(f32x4*)(effw + idx) = e;
        }
    }
}

// One wave per output channel o. lane = batch index b (64 = 64, exact).
// seg[o][i][s] is wave-uniform per i -> uniform float4 loads (1 line/instr).
// x delivered via xT[i][b] -> one coalesced dword per lane per i.
// No LDS, no barriers, no conversions; inner loop = pk-fma chains.
__global__ __launch_bounds__(64, 4)
void main_kernel(const float* __restrict__ xT,
                 const float* __restrict__ effw,
                 const float* __restrict__ seg,
                 const float* __restrict__ bias,
                 const float* __restrict__ aact,
                 const float* __restrict__ athr,
                 const float* __restrict__ gates,
                 const float* __restrict__ ws_ctx,
                 float* __restrict__ out) {
    const int lane = threadIdx.x;      // = b
    const int o = blockIdx.x;

    // mean_astro: lane-parallel over batch, xor-reduce
    const float aa = aact[o], th = athr[o];
    float sg = sigmoidf_(ws_ctx[lane] * aa);
    float ma = (sg > th) ? sg : 0.0f;
#pragma unroll
    for (int m = 32; m; m >>= 1) ma += __shfl_xor(ma, m, 64);
    const float mastro = ma * (1.0f / (float)Bn);

    const float* sp = seg + (size_t)o * In * Sn;   // contiguous 80 KB chunk
    const float* ep = effw + (size_t)o * In;
    const float* xp = xT + lane;

    f32x2 acc2[5];
#pragma unroll
    for (int k = 0; k < 5; ++k) acc2[k] = (f32x2){0.f, 0.f};
    float asyn = 0.0f;

    // 4 i's per group: 40 seg floats = 10 uniform float4 + 1 effw float4
    // + 4 coalesced x dwords + 20 pk-fma + 4 fma.
#pragma unroll 4
    for (int g = 0; g < In / 4; ++g) {
        const float* s4 = sp + g * 40;
        f32x4 q0 = *(const f32x4*)(s4 + 0);
        f32x4 q1 = *(const f32x4*)(s4 + 4);
        f32x4 q2 = *(const f32x4*)(s4 + 8);
        f32x4 q3 = *(const f32x4*)(s4 + 12);
        f32x4 q4 = *(const f32x4*)(s4 + 16);
        f32x4 q5 = *(const f32x4*)(s4 + 20);
        f32x4 q6 = *(const f32x4*)(s4 + 24);
        f32x4 q7 = *(const f32x4*)(s4 + 28);
        f32x4 q8 = *(const f32x4*)(s4 + 32);
        f32x4 q9 = *(const f32x4*)(s4 + 36);
        f32x4 ew = *(const f32x4*)(ep + g * 4);
        const float x0 = xp[(size_t)(g * 4 + 0) * Bn];
        const float x1 = xp[(size_t)(g * 4 + 1) * Bn];
        const float x2 = xp[(size_t)(g * 4 + 2) * Bn];
        const float x3 = xp[(size_t)(g * 4 + 3) * Bn];

        f32x2 xx;
        xx = (f32x2){x0, x0};
        acc2[0] += xx * (f32x2){q0[0], q0[1]};
        acc2[1] += xx * (f32x2){q0[2], q0[3]};
        acc2[2] += xx * (f32x2){q1[0], q1[1]};
        acc2[3] += xx * (f32x2){q1[2], q1[3]};
        acc2[4] += xx * (f32x2){q2[0], q2[1]};
        xx = (f32x2){x1, x1};
        acc2[0] += xx * (f32x2){q2[2], q2[3]};
        acc2[1] += xx * (f32x2){q3[0], q3[1]};
        acc2[2] += xx * (f32x2){q3[2], q3[3]};
        acc2[3] += xx * (f32x2){q4[0], q4[1]};
        acc2[4] += xx * (f32x2){q4[2], q4[3]};
        xx = (f32x2){x2, x2};
        acc2[0] += xx * (f32x2){q5[0], q5[1]};
        acc2[1] += xx * (f32x2){q5[2], q5[3]};
        acc2[2] += xx * (f32x2){q6[0], q6[1]};
        acc2[3] += xx * (f32x2){q6[2], q6[3]};
        acc2[4] += xx * (f32x2){q7[0], q7[1]};
        xx = (f32x2){x3, x3};
        acc2[0] += xx * (f32x2){q7[2], q7[3]};
        acc2[1] += xx * (f32x2){q8[0], q8[1]};
        acc2[2] += xx * (f32x2){q8[2], q8[3]};
        acc2[3] += xx * (f32x2){q9[0], q9[1]};
        acc2[4] += xx * (f32x2){q9[2], q9[3]};

        asyn = fmaf(ew[0], x0, asyn);
        asyn = fmaf(ew[1], x1, asyn);
        asyn = fmaf(ew[2], x2, asyn);
        asyn = fmaf(ew[3], x3, asyn);
    }

    // epilogue (per lane = per b): relu(dend)*gate sum + mastro*syn + bias
    float dend = 0.0f;
#pragma unroll
    for (int s2 = 0; s2 < 5; ++s2) {
#pragma unroll
        for (int h = 0; h < 2; ++h) {
            float v = acc2[s2][h];
            v = v > 0.0f ? v : 0.0f;
            dend += v * sigmoidf_(gates[o * Sn + s2 * 2 + h]);
        }
    }
    const float r = dend + mastro * asyn + bias[o];
    out[(size_t)lane * On + o] = r > 0.0f ? r : 0.0f;
}

extern "C" void kernel_launch(void* const* d_in, const int* in_sizes, int n_in,
                              void* d_out, int out_size, void* d_ws, size_t ws_size,
                              hipStream_t stream) {
    (void)in_sizes; (void)n_in; (void)out_size; (void)ws_size;
    const float* x    = (const float*)d_in[0];
    const float* ctx  = (const float*)d_in[1];
    // d_in[2] prev_activation: unused by the reference
    const float* wgt  = (const float*)d_in[3];
    const float* bias = (const float*)d_in[4];
    const float* aact = (const float*)d_in[5];
    const float* athr = (const float*)d_in[6];
    const float* seg  = (const float*)d_in[7];
    const float* gat  = (const float*)d_in[8];
    const float* cst  = (const float*)d_in[9];
    const float* prn  = (const float*)d_in[10];
    float* out = (float*)d_out;

    float* ws_ctx = (float*)d_ws;                                  // 256 B
    float* xT     = (float*)((char*)d_ws + 256);                   // 512 KB
    float* effw   = (float*)((char*)d_ws + 256 + In * Bn * 4);     // 16.8 MB

    prep_kernel<<<Bn + 32 + 512, 256, 0, stream>>>(x, ctx, wgt, cst, prn,
                                                   ws_ctx, xT, effw);
    main_kernel<<<On, 64, 0, stream>>>(xT, effw, seg, bias, aact, athr,
                                       gat, ws_ctx, out);
}

// Round 7
// 301.360 us; speedup vs baseline: 1.9150x; 1.9150x over previous
//
#include <hip/hip_runtime.h>
#include <math.h>

#define Bn 64
#define In 2048
#define On 2048
#define Sn 10
#define Cn 512

#define KT 64              // K tile
#define NT (In / KT)       // 32 K-tiles
#define LROW 72            // LDS row stride in bf16 elems (KT + 8)
#define NR 16              // LDS rows: 10 dendrite + 1 weight + 5 zero pad

typedef short short8 __attribute__((ext_vector_type(8)));
typedef float f32x4 __attribute__((ext_vector_type(4)));

__device__ __forceinline__ unsigned short f2bf(float f) {
    union { float f; unsigned u; } v; v.f = f;
    unsigned r = (v.u + 0x7FFFu + ((v.u >> 16) & 1u)) >> 16;  // RNE
    return (unsigned short)r;
}
__device__ __forceinline__ float sigmoidf_(float x) { return 1.0f / (1.0f + expf(-x)); }

// blocks 0..63: ctx_signal[b] = mean(context[b,:]); blocks 64..575: x -> bf16
__global__ void prep_kernel(const float* __restrict__ x,
                            const float* __restrict__ ctx,
                            float* __restrict__ ws_ctx,
                            unsigned short* __restrict__ ws_xbf) {
    const int b = blockIdx.x;
    const int t = threadIdx.x;
    if (b < Bn) {
        __shared__ float red[256];
        float s = ctx[b * Cn + t] + ctx[b * Cn + t + 256];
        red[t] = s;
        __syncthreads();
        for (int off = 128; off > 0; off >>= 1) {
            if (t < off) red[t] += red[t + off];
            __syncthreads();
        }
        if (t == 0) ws_ctx[b] = red[0] * (1.0f / (float)Cn);
    } else {
        int idx = (b - Bn) * 256 + t;
        ws_xbf[idx] = f2bf(x[idx]);
    }
}

// ---- fully named register staging (no arrays -> no scratch; rule #20) ----
#define LOADSEG(N, tile) do {                                                  \
    const float* p_ = segbase + (size_t)(tile) * (KT * Sn);                    \
    s##N##_0 = *(const float2*)(p_ + so0);                                     \
    s##N##_1 = *(const float2*)(p_ + so1);                                     \
    s##N##_2 = *(const float2*)(p_ + so2);                                     \
    s##N##_3 = *(const float2*)(p_ + so3);                                     \
    s##N##_4 = *(const float2*)(p_ + so4);                                     \
    w##N = wrow[(tile) * KT + lane];                                           \
    c##N = crow[(tile) * KT + lane];                                           \
} while (0)

#define LOADA(P, tile) do {                                                    \
    const unsigned short* p_ = xrow + (tile) * KT;                             \
    a##P##_00 = *(const short8*)(p_);                                          \
    a##P##_01 = *(const short8*)(p_ + 32);                                     \
    a##P##_10 = *(const short8*)(p_ + 16 * In);                                \
    a##P##_11 = *(const short8*)(p_ + 16 * In + 32);                           \
    a##P##_20 = *(const short8*)(p_ + 32 * In);                                \
    a##P##_21 = *(const short8*)(p_ + 32 * In + 32);                           \
    a##P##_30 = *(const short8*)(p_ + 48 * In);                                \
    a##P##_31 = *(const short8*)(p_ + 48 * In + 32);                           \
} while (0)

#define STOREB(N, Bl) do {                                                     \
    Bl[lo0] = f2bf(s##N##_0.x);  Bl[lo0 + LROW] = f2bf(s##N##_0.y);            \
    Bl[lo1] = f2bf(s##N##_1.x);  Bl[lo1 + LROW] = f2bf(s##N##_1.y);            \
    Bl[lo2] = f2bf(s##N##_2.x);  Bl[lo2 + LROW] = f2bf(s##N##_2.y);            \
    Bl[lo3] = f2bf(s##N##_3.x);  Bl[lo3 + LROW] = f2bf(s##N##_3.y);            \
    Bl[lo4] = f2bf(s##N##_4.x);  Bl[lo4 + LROW] = f2bf(s##N##_4.y);            \
    const float e_ = (__builtin_fabsf(w##N) * c##N > pthr) ? w##N : 0.0f;      \
    Bl[10 * LROW + lane] = f2bf(e_);                                           \
} while (0)

#define COMPUTE(Bl, P) do {                                                    \
    const unsigned short* Bp_ = &Bl[l15 * LROW + q * 8];                       \
    short8 b0_ = *(const short8*)(Bp_);                                        \
    short8 b1_ = *(const short8*)(Bp_ + 32);                                   \
    acc0 = __builtin_amdgcn_mfma_f32_16x16x32_bf16(a##P##_00, b0_, acc0, 0, 0, 0); \
    acc0 = __builtin_amdgcn_mfma_f32_16x16x32_bf16(a##P##_01, b1_, acc0, 0, 0, 0); \
    acc1 = __builtin_amdgcn_mfma_f32_16x16x32_bf16(a##P##_10, b0_, acc1, 0, 0, 0); \
    acc1 = __builtin_amdgcn_mfma_f32_16x16x32_bf16(a##P##_11, b1_, acc1, 0, 0, 0); \
    acc2 = __builtin_amdgcn_mfma_f32_16x16x32_bf16(a##P##_20, b0_, acc2, 0, 0, 0); \
    acc2 = __builtin_amdgcn_mfma_f32_16x16x32_bf16(a##P##_21, b1_, acc2, 0, 0, 0); \
    acc3 = __builtin_amdgcn_mfma_f32_16x16x32_bf16(a##P##_30, b0_, acc3, 0, 0, 0); \
    acc3 = __builtin_amdgcn_mfma_f32_16x16x32_bf16(a##P##_31, b1_, acc3, 0, 0, 0); \
} while (0)

// One wave per output channel o; no barriers; wave-private double LDS buffer.
// Per step tau: A(tau+1) issued FIRST (so compute(tau)'s in-order vmcnt wait
// targets the OLDEST outstanding group and leaves seg prefetches in flight),
// then seg(tau+4) prefetch, then compute(tau), then store(tau+2) (its loads
// are 2 steps old -> wait already satisfied).
__global__ __launch_bounds__(64, 2)
void main_kernel(const unsigned short* __restrict__ xbf,
                 const float* __restrict__ wgt,
                 const float* __restrict__ cst,
                 const float* __restrict__ seg,
                 const float* __restrict__ bias,
                 const float* __restrict__ aact,
                 const float* __restrict__ athr,
                 const float* __restrict__ gates,
                 const float* __restrict__ prn,
                 const float* __restrict__ ws_ctx,
                 float* __restrict__ out) {
    __shared__ __align__(16) unsigned short Blds0[NR * LROW];
    __shared__ __align__(16) unsigned short Blds1[NR * LROW];

    const int lane = threadIdx.x;       // 0..63
    const int o = blockIdx.x;           // one o per wave
    const int l15 = lane & 15;
    const int q = lane >> 4;
    const float pthr = prn[0];

    // zero pad rows 11..15 (in-wave order guarantees visibility; never rewritten)
    for (int idx = lane; idx < 5 * LROW; idx += 64) {
        Blds0[11 * LROW + idx] = 0;
        Blds1[11 * LROW + idx] = 0;
    }

    // mean_astro: lane-parallel over batch, xor-reduce (all lanes get result)
    const float aa = aact[o], th = athr[o];
    float sgv = sigmoidf_(ws_ctx[lane] * aa);
    float ma = (sgv > th) ? sgv : 0.0f;
#pragma unroll
    for (int m = 32; m; m >>= 1) ma += __shfl_xor(ma, m, 64);
    const float mastro = ma * (1.0f / (float)Bn);

    // dendritic gate sigmoid for this lane's n-row
    const float gsig = (l15 < 10) ? sigmoidf_(gates[o * Sn + l15]) : 0.0f;

    // seg flat staging offsets: f = lane + 64j -> byte offset 8f (fully coalesced)
    int so0, so1, so2, so3, so4, lo0, lo1, lo2, lo3, lo4;
    {
        int f, io, s2;
        f = lane;       io = f / 5; s2 = (f - io * 5) * 2; so0 = io * Sn + s2; lo0 = s2 * LROW + io;
        f = lane + 64;  io = f / 5; s2 = (f - io * 5) * 2; so1 = io * Sn + s2; lo1 = s2 * LROW + io;
        f = lane + 128; io = f / 5; s2 = (f - io * 5) * 2; so2 = io * Sn + s2; lo2 = s2 * LROW + io;
        f = lane + 192; io = f / 5; s2 = (f - io * 5) * 2; so3 = io * Sn + s2; lo3 = s2 * LROW + io;
        f = lane + 256; io = f / 5; s2 = (f - io * 5) * 2; so4 = io * Sn + s2; lo4 = s2 * LROW + io;
    }
    const float* segbase = seg + (size_t)o * In * Sn;
    const float* wrow = wgt + (size_t)o * In;
    const float* crow = cst + (size_t)o * In;
    const unsigned short* xrow = xbf + (size_t)l15 * In + q * 8;

    // named staging registers: 4 seg sets (tile mod 4), 2 A sets (tile parity)
    float2 sA_0, sA_1, sA_2, sA_3, sA_4; float wA, cA;
    float2 sB_0, sB_1, sB_2, sB_3, sB_4; float wB, cB;
    float2 sC_0, sC_1, sC_2, sC_3, sC_4; float wC, cC;
    float2 sD_0, sD_1, sD_2, sD_3, sD_4; float wD, cD;
    short8 aE_00, aE_01, aE_10, aE_11, aE_20, aE_21, aE_30, aE_31;
    short8 aO_00, aO_01, aO_10, aO_11, aO_20, aO_21, aO_30, aO_31;

    f32x4 acc0 = (f32x4){0.f, 0.f, 0.f, 0.f};
    f32x4 acc1 = (f32x4){0.f, 0.f, 0.f, 0.f};
    f32x4 acc2 = (f32x4){0.f, 0.f, 0.f, 0.f};
    f32x4 acc3 = (f32x4){0.f, 0.f, 0.f, 0.f};

    // ---- prologue: fill seg sets for tiles 0..3, A for tile 0, stage 0/1 ----
    LOADSEG(A, 0); LOADSEG(B, 1); LOADSEG(C, 2); LOADSEG(D, 3);
    LOADA(E, 0);
    STOREB(A, Blds0); STOREB(B, Blds1);

    // ---- steady state: steps tau = 0..27, unrolled x4 ----
    for (int u = 0; u < 7; ++u) {
        const int t4 = u * 4;
        LOADA(O, t4 + 1); LOADSEG(A, t4 + 4); COMPUTE(Blds0, E); STOREB(C, Blds0);
        LOADA(E, t4 + 2); LOADSEG(B, t4 + 5); COMPUTE(Blds1, O); STOREB(D, Blds1);
        LOADA(O, t4 + 3); LOADSEG(C, t4 + 6); COMPUTE(Blds0, E); STOREB(A, Blds0);
        LOADA(E, t4 + 4); LOADSEG(D, t4 + 7); COMPUTE(Blds1, O); STOREB(B, Blds1);
    }

    // ---- epilogue: steps 28..31 (no more seg loads) ----
    LOADA(O, 29); COMPUTE(Blds0, E); STOREB(C, Blds0);   // tau=28, store tile 30
    LOADA(E, 30); COMPUTE(Blds1, O); STOREB(D, Blds1);   // tau=29, store tile 31
    LOADA(O, 31); COMPUTE(Blds0, E);                     // tau=30
    COMPUTE(Blds1, O);                                   // tau=31

    // ---- output: cross-lane reduce over n (l15); no LDS, no atomics ----
    // acc{mt}[r] = D[b = mt*16 + q*4 + r][n = l15]
    const float bo = bias[o];
#define EPI(accv, mt) do {                                                     \
    _Pragma("unroll")                                                          \
    for (int r = 0; r < 4; ++r) {                                              \
        const float v = accv[r];                                               \
        float contrib;                                                         \
        if (l15 < 10)       contrib = (v > 0.f ? v : 0.f) * gsig;              \
        else if (l15 == 10) contrib = mastro * v;                              \
        else                contrib = 0.f;                                     \
        contrib += __shfl_xor(contrib, 1, 64);                                 \
        contrib += __shfl_xor(contrib, 2, 64);                                 \
        contrib += __shfl_xor(contrib, 4, 64);                                 \
        contrib += __shfl_xor(contrib, 8, 64);                                 \
        if (l15 == 0) {                                                        \
            const int b_ = (mt) * 16 + q * 4 + r;                              \
            const float ov = contrib + bo;                                     \
            out[(size_t)b_ * On + o] = ov > 0.f ? ov : 0.f;                    \
        }                                                                      \
    }                                                                          \
} while (0)
    EPI(acc0, 0); EPI(acc1, 1); EPI(acc2, 2); EPI(acc3, 3);
#undef EPI
}

extern "C" void kernel_launch(void* const* d_in, const int* in_sizes, int n_in,
                              void* d_out, int out_size, void* d_ws, size_t ws_size,
                              hipStream_t stream) {
    (void)in_sizes; (void)n_in; (void)out_size; (void)ws_size;
    const float* x    = (const float*)d_in[0];
    const float* ctx  = (const float*)d_in[1];
    // d_in[2] prev_activation: unused by the reference
    const float* wgt  = (const float*)d_in[3];
    const float* bias = (const float*)d_in[4];
    const float* aact = (const float*)d_in[5];
    const float* athr = (const float*)d_in[6];
    const float* seg  = (const float*)d_in[7];
    const float* gat  = (const float*)d_in[8];
    const float* cst  = (const float*)d_in[9];
    const float* prn  = (const float*)d_in[10];
    float* out = (float*)d_out;

    float* ws_ctx = (float*)d_ws;
    unsigned short* ws_xbf = (unsigned short*)((char*)d_ws + 256);

    prep_kernel<<<Bn + (Bn * In) / 256, 256, 0, stream>>>(x, ctx, ws_ctx, ws_xbf);
    main_kernel<<<On, 64, 0, stream>>>(ws_xbf, wgt, cst, seg, bias, aact,
                                       athr, gat, prn, ws_ctx, out);
}